// Round 1
// baseline (2277.276 us; speedup 1.0000x reference)
//
#include <hip/hip_runtime.h>

// Problem: act[n,b,o] = (sum_i x[b,i]*W[i,o]*(noise[n,i,o]-1)) / r[b,o]
//          r[b,o]     = sqrt(sum_i x[b,i]^2 * W[i,o]^2)
// (column norms of W cancel exactly between numerator and denominator)
//
// B=128, IN=784 (=49*16), OUT=1024, NITER=500. Memory-bound: noise = 1.605 GB.

#define B_DIM   128
#define IN_DIM  784
#define OUT_DIM 1024
#define NITER   500
#define KSTEPS  49      // 784 / 16 (one mfma_32x32x16 K-step = 16)
#define KK_DIM  98      // 784 / 8  (8-row groups; lane's frag = 8 consecutive k)

typedef __attribute__((ext_vector_type(8)))  short short8;
typedef __attribute__((ext_vector_type(4)))  float floatx4;
typedef __attribute__((ext_vector_type(16))) float floatx16;

// f32 -> bf16 round-to-nearest-even (3 VALU ops, no header dependency)
__device__ __forceinline__ short f2bf(float f) {
    unsigned u = __builtin_bit_cast(unsigned, f);
    unsigned r = (u + 0x7FFFu + ((u >> 16) & 1u)) >> 16;
    return (short)(unsigned short)r;
}

// ---- precompute: x in fragment-ordered bf16 (and x^2 for the r-GEMM) ----
// layout xf[(kk*128 + m)*8 + j] = bf16(x[m][kk*8+j]) ; 16B per (kk,m) chunk
__global__ void __launch_bounds__(256) prep_x_kernel(const float* __restrict__ x,
                                                     short* __restrict__ xf,
                                                     short* __restrict__ x2f) {
    int tid = blockIdx.x * 256 + threadIdx.x;        // 98*128 = 12544 threads
    if (tid >= KK_DIM * B_DIM) return;
    int m  = tid & (B_DIM - 1);
    int kk = tid >> 7;
    int src = m * IN_DIM + kk * 8;
    int dst = (kk * B_DIM + m) * 8;
#pragma unroll
    for (int j = 0; j < 8; ++j) {
        float v = x[src + j];
        xf[dst + j]  = f2bf(v);
        x2f[dst + j] = f2bf(v * v);
    }
}

// ---- precompute: W fragment-ordered f32 (and W^2 bf16 for the r-GEMM) ----
// layout Wf[(kk*1024 + o)*8 + j] = W[kk*8+j][o]
__global__ void __launch_bounds__(256) prep_w_kernel(const float* __restrict__ W,
                                                     float* __restrict__ Wf,
                                                     short* __restrict__ W2f) {
    int tid = blockIdx.x * 256 + threadIdx.x;        // 98*1024 = 100352 threads
    if (tid >= KK_DIM * OUT_DIM) return;
    int o  = tid & (OUT_DIM - 1);
    int kk = tid >> 10;
    int dst = (kk * OUT_DIM + o) * 8;
#pragma unroll
    for (int j = 0; j < 8; ++j) {
        float v = W[(kk * 8 + j) * OUT_DIM + o];
        Wf[dst + j]  = v;
        W2f[dst + j] = f2bf(v * v);
    }
}

// ---- r-GEMM: invr[b,o] = rsqrt( (x^2) @ (W^2) ), via 32x32x16 bf16 MFMA ----
__global__ void __launch_bounds__(256) rnorm_kernel(const short* __restrict__ x2f,
                                                    const short* __restrict__ w2f,
                                                    float* __restrict__ invr) {
    int ot   = blockIdx.x;                 // 8 o-tiles of 128
    int tid  = threadIdx.x;
    int wave = tid >> 6, lane = tid & 63;
    int wm = wave & 1, wn = wave >> 1;
    int p = lane & 31, h = lane >> 5;
    int m_base = wm * 64;
    int o_base = ot * 128 + wn * 64;

    floatx16 acc[2][2] = {};
    for (int ks = 0; ks < KSTEPS; ++ks) {
        int kk = ks * 2 + h;
        short8 a[2], b[2];
#pragma unroll
        for (int mt = 0; mt < 2; ++mt)
            a[mt] = *(const short8*)(x2f + (kk * B_DIM + m_base + mt * 32 + p) * 8);
#pragma unroll
        for (int nt = 0; nt < 2; ++nt)
            b[nt] = *(const short8*)(w2f + (kk * OUT_DIM + o_base + nt * 32 + p) * 8);
#pragma unroll
        for (int mt = 0; mt < 2; ++mt)
#pragma unroll
            for (int nt = 0; nt < 2; ++nt)
                acc[mt][nt] = __builtin_amdgcn_mfma_f32_32x32x16_bf16(a[mt], b[nt], acc[mt][nt], 0, 0, 0);
    }
#pragma unroll
    for (int mt = 0; mt < 2; ++mt)
#pragma unroll
        for (int nt = 0; nt < 2; ++nt)
#pragma unroll
            for (int reg = 0; reg < 16; ++reg) {
                int r   = (reg & 3) + 8 * (reg >> 2) + 4 * h;   // measured C/D layout
                int row = m_base + mt * 32 + r;
                int col = o_base + nt * 32 + p;
                invr[row * OUT_DIM + col] = rsqrtf(acc[mt][nt][reg]);
            }
}

// ---- main: act[n] = (x @ (W .* (noise[n]-1))) * invr, fused transform, no LDS ----
__global__ void __launch_bounds__(256) wnorm_main_kernel(const short* __restrict__ xf,
                                                         const float* __restrict__ Wf,
                                                         const float* __restrict__ noise,
                                                         const float* __restrict__ invr,
                                                         float* __restrict__ out) {
    int bx = blockIdx.x;
    int ot = bx & 7;          // o-tile first -> stable XCD affinity for W/invr slices
    int n  = bx >> 3;
    int tid  = threadIdx.x;
    int wave = tid >> 6, lane = tid & 63;
    int wm = wave & 1, wn = wave >> 1;
    int p = lane & 31, h = lane >> 5;
    int m_base = wm * 64;
    int o_base = ot * 128 + wn * 64;
    const float* nbase = noise + (size_t)n * (IN_DIM * OUT_DIM);

    floatx16 acc[2][2] = {};
    for (int ks = 0; ks < KSTEPS; ++ks) {
        int kk = ks * 2 + h;
        // noise (HBM stream): 8 k-rows x (o = lane&31 consecutive) -> 2 full 128B lines/instr
        float nv[2][8];
        const float* np0 = nbase + (size_t)(kk * 8) * OUT_DIM + o_base + p;
#pragma unroll
        for (int nt = 0; nt < 2; ++nt) {
            const float* np = np0 + nt * 32;
#pragma unroll
            for (int j = 0; j < 8; ++j)
                nv[nt][j] = np[(size_t)j * OUT_DIM];
        }
        // W frags (f32, fragment-ordered, L2-resident): 2x dwordx4 each
        floatx4 w0[2], w1[2];
#pragma unroll
        for (int nt = 0; nt < 2; ++nt) {
            const float* wp = Wf + (kk * OUT_DIM + o_base + nt * 32 + p) * 8;
            w0[nt] = *(const floatx4*)(wp);
            w1[nt] = *(const floatx4*)(wp + 4);
        }
        // A frags (bf16, fragment-ordered, L2-resident): 1x dwordx4 each
        short8 a[2];
#pragma unroll
        for (int mt = 0; mt < 2; ++mt)
            a[mt] = *(const short8*)(xf + (kk * B_DIM + m_base + mt * 32 + p) * 8);
        // transform: b' = bf16( W * (noise - 1) ) = bf16( fma(W, noise, -W) )
        short8 b[2];
#pragma unroll
        for (int nt = 0; nt < 2; ++nt) {
            short8 t;
#pragma unroll
            for (int j = 0; j < 4; ++j) {
                t[j]     = f2bf(fmaf(w0[nt][j], nv[nt][j],     -w0[nt][j]));
                t[j + 4] = f2bf(fmaf(w1[nt][j], nv[nt][j + 4], -w1[nt][j]));
            }
            b[nt] = t;
        }
#pragma unroll
        for (int mt = 0; mt < 2; ++mt)
#pragma unroll
            for (int nt = 0; nt < 2; ++nt)
                acc[mt][nt] = __builtin_amdgcn_mfma_f32_32x32x16_bf16(a[mt], b[nt], acc[mt][nt], 0, 0, 0);
    }

    // epilogue: scale by invr (L2-resident), nontemporal store (output never re-read)
#pragma unroll
    for (int mt = 0; mt < 2; ++mt)
#pragma unroll
        for (int nt = 0; nt < 2; ++nt) {
            floatx16 av = acc[mt][nt];
#pragma unroll
            for (int reg = 0; reg < 16; ++reg) {
                int r   = (reg & 3) + 8 * (reg >> 2) + 4 * h;
                int row = m_base + mt * 32 + r;
                int col = o_base + nt * 32 + p;
                float val = av[reg] * invr[row * OUT_DIM + col];
                __builtin_nontemporal_store(val, out + (size_t)(n * B_DIM + row) * OUT_DIM + col);
            }
        }
}

extern "C" void kernel_launch(void* const* d_in, const int* in_sizes, int n_in,
                              void* d_out, int out_size, void* d_ws, size_t ws_size,
                              hipStream_t stream) {
    const float* x     = (const float*)d_in[0];   // [128, 784]
    const float* W     = (const float*)d_in[1];   // [784, 1024]
    const float* noise = (const float*)d_in[2];   // [500, 784, 1024]
    float* out = (float*)d_out;                   // [500*128, 1024]

    // workspace layout (needs ~5.75 MB)
    char* ws = (char*)d_ws;
    short* xf   = (short*)(ws);                   // 98*128*8 bf16  = 200704 B
    short* x2f  = (short*)(ws + 200704);          // 200704 B
    float* Wf   = (float*)(ws + 401408);          // 98*1024*8 f32  = 3211264 B
    short* W2f  = (short*)(ws + 3612672);         // 1605632 B
    float* invr = (float*)(ws + 5218304);         // 128*1024 f32   = 524288 B

    prep_x_kernel<<<dim3(49),   dim3(256), 0, stream>>>(x, xf, x2f);
    prep_w_kernel<<<dim3(392),  dim3(256), 0, stream>>>(W, Wf, W2f);
    rnorm_kernel <<<dim3(8),    dim3(256), 0, stream>>>(x2f, W2f, invr);
    wnorm_main_kernel<<<dim3(4000), dim3(256), 0, stream>>>(xf, Wf, noise, invr, out);
}